// Round 5
// baseline (440.519 us; speedup 1.0000x reference)
//
#include <hip/hip_runtime.h>
#include <math.h>

// Problem constants (fixed by the reference file)
constexpr int B = 256;
constexpr int L = 1024;
constexpr int D = 512;
constexpr int DV = D / 4;                         // 128 float4 per row
constexpr float INV_T = 0.044194173824159216f;    // 1/sqrt(512)

typedef float f4nt __attribute__((ext_vector_type(4)));
__device__ __forceinline__ void nt_store4(float4* p, float4 val) {
    __builtin_nontemporal_store(*reinterpret_cast<f4nt*>(&val),
                                reinterpret_cast<f4nt*>(p));
}

// Persistent pipelined kernel: 512 blocks x 512 threads; block (b, h) owns
// rows [h*512, h*512+512) of batch b. Cross-block sync only between the two
// sibling blocks of a batch, via device-scope atomics (no global barriers).
__global__ __launch_bounds__(512, 4) void cda_pipe(
    const float* __restrict__ q,    // (B,1,D)
    const float* __restrict__ kc,   // (B,L,D)
    const float* __restrict__ kd,   // (B,L,D)
    const float* __restrict__ v,    // (B,L,D)
    float* __restrict__ out,        // (B,L,D)
    float* __restrict__ logits,     // (B,L)
    float* __restrict__ expm,       // (B*2) ws: per-half logit max
    float* __restrict__ exps,       // (B*2) ws: per-half exp-sum
    float* __restrict__ partial,    // (B*2*D) ws: per-half partial attn
    unsigned* __restrict__ ctr1,    // (B) ws: logits-done counters
    unsigned* __restrict__ ctr2)    // (B) ws: partial-done counters
{
    const int bid = blockIdx.x;
    const int b   = bid >> 1;
    const int h   = bid & 1;
    const int sib = bid ^ 1;
    const int tid  = threadIdx.x;
    const int lane = tid & 63;
    const int wave = tid >> 6;      // 0..7
    const int t16  = tid & 15;
    const int grp  = tid >> 4;      // 0..31 row-groups

    __shared__ float  s_log[512];       // logits -> softmax weights (in place)
    __shared__ float  s_gate[512];
    __shared__ float4 s_part[4][DV];    // 8 KB
    __shared__ float4 s_attn[DV];       // 2 KB
    __shared__ float  s_red[8];
    __shared__ float  s_red2[8];
    __shared__ float  s_bc[2];          // gm, 1/gs broadcast

    // ---- q fragment for this lane's 16-lane group ----
    const float4* q4 = reinterpret_cast<const float4*>(q + (size_t)b * D);
    float4 qr[8];
    #pragma unroll
    for (int k = 0; k < 8; ++k) qr[k] = q4[t16 + k * 16];

    const size_t rowbase = (size_t)b * L + (size_t)h * 512;
    const float4* kc4 = reinterpret_cast<const float4*>(kc) + rowbase * DV;
    const float4* kd4 = reinterpret_cast<const float4*>(kd) + rowbase * DV;

    // ---- P1: logits + gates for my 512 rows (32 rows per iteration) ----
    #pragma unroll 2
    for (int it = 0; it < 16; ++it) {
        const int lr = it * 32 + grp;    // local row 0..511
        const float4* rowc = kc4 + (size_t)lr * DV + t16;
        const float4* rowd = kd4 + (size_t)lr * DV + t16;
        float dc = 0.f, dd = 0.f;
        #pragma unroll
        for (int k = 0; k < 8; ++k) {
            const float4 c = rowc[k * 16];
            const float4 e = rowd[k * 16];
            dc += qr[k].x * c.x + qr[k].y * c.y + qr[k].z * c.z + qr[k].w * c.w;
            dd += qr[k].x * e.x + qr[k].y * e.y + qr[k].z * e.z + qr[k].w * e.w;
        }
        dc += __shfl_xor(dc, 8); dd += __shfl_xor(dd, 8);
        dc += __shfl_xor(dc, 4); dd += __shfl_xor(dd, 4);
        dc += __shfl_xor(dc, 2); dd += __shfl_xor(dd, 2);
        dc += __shfl_xor(dc, 1); dd += __shfl_xor(dd, 1);
        if (t16 == 0) {
            s_log[lr]  = dc * INV_T;
            s_gate[lr] = 1.0f / (1.0f + __expf(-dd * INV_T));
        }
    }
    __syncthreads();

    // ---- logits output + per-half (max, expsum) ----
    const float x = s_log[tid];
    logits[rowbase + tid] = x;

    float m = x;
    #pragma unroll
    for (int off = 32; off; off >>= 1) m = fmaxf(m, __shfl_xor(m, off));
    if (lane == 0) s_red[wave] = m;
    __syncthreads();
    float mh = s_red[0];
    #pragma unroll
    for (int i = 1; i < 8; ++i) mh = fmaxf(mh, s_red[i]);

    float ex = __expf(x - mh);
    float ss = ex;
    #pragma unroll
    for (int off = 32; off; off >>= 1) ss += __shfl_xor(ss, off);
    if (lane == 0) s_red2[wave] = ss;
    __syncthreads();

    if (tid == 0) {
        float sh = s_red2[0];
        #pragma unroll
        for (int i = 1; i < 8; ++i) sh += s_red2[i];
        __hip_atomic_store(&expm[bid], mh, __ATOMIC_RELAXED, __HIP_MEMORY_SCOPE_AGENT);
        __hip_atomic_store(&exps[bid], sh, __ATOMIC_RELAXED, __HIP_MEMORY_SCOPE_AGENT);
        __hip_atomic_fetch_add(&ctr1[b], 1u, __ATOMIC_RELEASE, __HIP_MEMORY_SCOPE_AGENT);
        while (__hip_atomic_load(&ctr1[b], __ATOMIC_ACQUIRE, __HIP_MEMORY_SCOPE_AGENT) < 2u)
            __builtin_amdgcn_s_sleep(4);
        const float m0 = __hip_atomic_load(&expm[sib], __ATOMIC_RELAXED, __HIP_MEMORY_SCOPE_AGENT);
        const float s0 = __hip_atomic_load(&exps[sib], __ATOMIC_RELAXED, __HIP_MEMORY_SCOPE_AGENT);
        const float gm = fmaxf(mh, m0);
        const float gs = sh * __expf(mh - gm) + s0 * __expf(m0 - gm);
        s_bc[0] = gm;
        s_bc[1] = 1.0f / gs;
    }
    __syncthreads();

    const float gm  = s_bc[0];
    const float rgs = s_bc[1];
    s_log[tid] = __expf(s_log[tid] - gm) * rgs;   // softmax weight, my rows
    __syncthreads();

    // ---- P2: partial attn over my 512 v rows ----
    const float4* v4 = reinterpret_cast<const float4*>(v) + rowbase * DV;
    const int c = tid & 127;          // float4 column
    const int g = tid >> 7;           // 0..3
    float4 acc0 = make_float4(0.f, 0.f, 0.f, 0.f);
    float4 acc1 = make_float4(0.f, 0.f, 0.f, 0.f);
    #pragma unroll 4
    for (int r = 0; r < 128; r += 2) {
        const int l0 = g * 128 + r;
        const float w0 = s_log[l0];
        const float w1 = s_log[l0 + 1];
        const float4 v0 = v4[(size_t)l0 * DV + c];
        const float4 v1 = v4[(size_t)(l0 + 1) * DV + c];
        acc0.x += w0 * v0.x; acc0.y += w0 * v0.y;
        acc0.z += w0 * v0.z; acc0.w += w0 * v0.w;
        acc1.x += w1 * v1.x; acc1.y += w1 * v1.y;
        acc1.z += w1 * v1.z; acc1.w += w1 * v1.w;
    }
    acc0.x += acc1.x; acc0.y += acc1.y; acc0.z += acc1.z; acc0.w += acc1.w;
    s_part[g][c] = acc0;
    __syncthreads();

    float4 mine;
    if (tid < DV) {
        const float4 p0 = s_part[0][tid];
        const float4 p1 = s_part[1][tid];
        const float4 p2 = s_part[2][tid];
        const float4 p3 = s_part[3][tid];
        mine.x = (p0.x + p1.x) + (p2.x + p3.x);
        mine.y = (p0.y + p1.y) + (p2.y + p3.y);
        mine.z = (p0.z + p1.z) + (p2.z + p3.z);
        mine.w = (p0.w + p1.w) + (p2.w + p3.w);
        float* dst = partial + (size_t)bid * D + tid * 4;
        __hip_atomic_store(dst + 0, mine.x, __ATOMIC_RELAXED, __HIP_MEMORY_SCOPE_AGENT);
        __hip_atomic_store(dst + 1, mine.y, __ATOMIC_RELAXED, __HIP_MEMORY_SCOPE_AGENT);
        __hip_atomic_store(dst + 2, mine.z, __ATOMIC_RELAXED, __HIP_MEMORY_SCOPE_AGENT);
        __hip_atomic_store(dst + 3, mine.w, __ATOMIC_RELAXED, __HIP_MEMORY_SCOPE_AGENT);
    }
    __syncthreads();   // all partial stores issued & drained (barrier waits vmcnt)

    if (tid == 0) {
        __hip_atomic_fetch_add(&ctr2[b], 1u, __ATOMIC_RELEASE, __HIP_MEMORY_SCOPE_AGENT);
        while (__hip_atomic_load(&ctr2[b], __ATOMIC_ACQUIRE, __HIP_MEMORY_SCOPE_AGENT) < 2u)
            __builtin_amdgcn_s_sleep(4);
    }
    __syncthreads();

    if (tid < DV) {
        const float* src = partial + (size_t)sib * D + tid * 4;
        float4 o;
        o.x = __hip_atomic_load(src + 0, __ATOMIC_RELAXED, __HIP_MEMORY_SCOPE_AGENT);
        o.y = __hip_atomic_load(src + 1, __ATOMIC_RELAXED, __HIP_MEMORY_SCOPE_AGENT);
        o.z = __hip_atomic_load(src + 2, __ATOMIC_RELAXED, __HIP_MEMORY_SCOPE_AGENT);
        o.w = __hip_atomic_load(src + 3, __ATOMIC_RELAXED, __HIP_MEMORY_SCOPE_AGENT);
        s_attn[tid] = make_float4(mine.x + o.x, mine.y + o.y,
                                  mine.z + o.z, mine.w + o.w);
    }
    __syncthreads();

    // ---- P3: out[l,:] = gate[l] * attn, my 512 rows, NT streaming stores ----
    float4* out4 = reinterpret_cast<float4*>(out) + rowbase * DV;
    #pragma unroll 4
    for (int i = tid; i < 512 * DV; i += 512) {
        const int l  = i >> 7;
        const int cc = i & 127;
        const float sg = s_gate[l];
        const float4 a = s_attn[cc];
        nt_store4(&out4[i], make_float4(sg * a.x, sg * a.y, sg * a.z, sg * a.w));
    }
}

extern "C" void kernel_launch(void* const* d_in, const int* in_sizes, int n_in,
                              void* d_out, int out_size, void* d_ws, size_t ws_size,
                              hipStream_t stream) {
    const float* q  = (const float*)d_in[0];
    const float* kc = (const float*)d_in[1];
    const float* kd = (const float*)d_in[2];
    const float* v  = (const float*)d_in[3];
    float* out    = (float*)d_out;                       // (B,L,D) flat
    float* logits = out + (size_t)B * L * D;             // (B,L) flat

    // ws layout: [ctr1 | ctr2 | expm | exps | partial]
    unsigned* ctr1 = (unsigned*)d_ws;                    // B
    unsigned* ctr2 = ctr1 + B;                           // B
    float* expm    = (float*)(ctr2 + B);                 // B*2
    float* exps    = expm + B * 2;                       // B*2
    float* partial = exps + B * 2;                       // B*2*D

    // counters must be zero every call (harness does not re-poison ws)
    hipMemsetAsync(d_ws, 0, 2 * B * sizeof(unsigned), stream);

    hipLaunchKernelGGL(cda_pipe, dim3(B * 2), dim3(512), 0, stream,
                       q, kc, kd, v, out, logits, expm, exps, partial, ctr1, ctr2);
}

// Round 6
// 368.899 us; speedup vs baseline: 1.1941x; 1.1941x over previous
//
#include <hip/hip_runtime.h>
#include <math.h>

// Problem constants (fixed by the reference file)
constexpr int B = 256;
constexpr int L = 1024;
constexpr int D = 512;
constexpr int DV = D / 4;                         // 128 float4 per row
constexpr float INV_T = 0.044194173824159216f;    // 1/sqrt(512)

typedef float f4nt __attribute__((ext_vector_type(4)));
__device__ __forceinline__ void nt_store4(float4* p, float4 val) {
    __builtin_nontemporal_store(*reinterpret_cast<f4nt*>(&val),
                                reinterpret_cast<f4nt*>(p));
}

// ============ K1: logits = q.kc / T ; gates = sigmoid(q.kd / T) ============
// grid = B*8 blocks, 256 threads. Block (b, rchunk) handles 128 rows.
__global__ __launch_bounds__(256) void cda_k1_logits(
    const float* __restrict__ q,
    const float* __restrict__ kc,
    const float* __restrict__ kd,
    float* __restrict__ logits,   // (B,L) in d_out tail
    float* __restrict__ gates)    // (B,L) in ws
{
    const int b      = blockIdx.x >> 3;
    const int rchunk = blockIdx.x & 7;
    const int l0     = rchunk * 128;
    const int tid    = threadIdx.x;
    const int t16    = tid & 15;
    const int grp    = tid >> 4;          // 0..15 row-groups

    __shared__ float s_log[128];
    __shared__ float s_gate[128];

    const float4* q4 = reinterpret_cast<const float4*>(q + (size_t)b * D);
    float4 qr[8];
    #pragma unroll
    for (int k = 0; k < 8; ++k) qr[k] = q4[t16 + k * 16];

    const float4* kc4 = reinterpret_cast<const float4*>(kc + (size_t)b * L * D);
    const float4* kd4 = reinterpret_cast<const float4*>(kd + (size_t)b * L * D);

    #pragma unroll 2
    for (int it = 0; it < 8; ++it) {
        const int lr = it * 16 + grp;     // row within chunk
        const int l  = l0 + lr;
        const float4* rowc = kc4 + (size_t)l * DV + t16;
        const float4* rowd = kd4 + (size_t)l * DV + t16;
        float dc = 0.f, dd = 0.f;
        #pragma unroll
        for (int k = 0; k < 8; ++k) {
            const float4 c = rowc[k * 16];
            const float4 e = rowd[k * 16];
            dc += qr[k].x * c.x + qr[k].y * c.y + qr[k].z * c.z + qr[k].w * c.w;
            dd += qr[k].x * e.x + qr[k].y * e.y + qr[k].z * e.z + qr[k].w * e.w;
        }
        dc += __shfl_xor(dc, 8); dd += __shfl_xor(dd, 8);
        dc += __shfl_xor(dc, 4); dd += __shfl_xor(dd, 4);
        dc += __shfl_xor(dc, 2); dd += __shfl_xor(dd, 2);
        dc += __shfl_xor(dc, 1); dd += __shfl_xor(dd, 1);
        if (t16 == 0) {
            s_log[lr]  = dc * INV_T;
            s_gate[lr] = 1.0f / (1.0f + __expf(-dd * INV_T));
        }
    }
    __syncthreads();

    if (tid < 128) {
        logits[(size_t)b * L + l0 + tid] = s_log[tid];
        gates [(size_t)b * L + l0 + tid] = s_gate[tid];
    }
}

// ====== K23: softmax + column-slice v-reduction + direct output write ======
// grid = B*4 blocks, 512 threads. Block (b, cg) owns float columns
// [cg*128, cg*128+128) = float4 cols [cg*32, cg*32+32).
// Reads all L logits+gates (8 KB), streams v[:, slice] (512 KB),
// writes out[:, slice] (512 KB) with NT stores. No cross-block deps.
__global__ __launch_bounds__(512) void cda_k23(
    const float* __restrict__ logits,
    const float* __restrict__ gates,
    const float* __restrict__ v,
    float* __restrict__ out)
{
    const int b    = blockIdx.x >> 2;
    const int cg   = blockIdx.x & 3;
    const int tid  = threadIdx.x;
    const int lane = tid & 63;
    const int wave = tid >> 6;        // 0..7

    __shared__ float  s_w[L];             // 4 KB softmax weights
    __shared__ float  s_gate[L];          // 4 KB gates
    __shared__ float4 s_acc[16][32];      // 8 KB partial column accumulators
    __shared__ float4 s_attn[32];         // my 32 float4 of attn
    __shared__ float  s_red[8];
    __shared__ float  s_red2[8];

    // ---- load logits + gates, softmax over L (redundant per cg - free) ----
    const float x0 = logits[(size_t)b * L + tid];
    const float x1 = logits[(size_t)b * L + tid + 512];
    s_gate[tid]       = gates[(size_t)b * L + tid];
    s_gate[tid + 512] = gates[(size_t)b * L + tid + 512];

    float m = fmaxf(x0, x1);
    #pragma unroll
    for (int off = 32; off; off >>= 1) m = fmaxf(m, __shfl_xor(m, off));
    if (lane == 0) s_red[wave] = m;
    __syncthreads();
    float gm = s_red[0];
    #pragma unroll
    for (int i = 1; i < 8; ++i) gm = fmaxf(gm, s_red[i]);

    const float e0 = __expf(x0 - gm);
    const float e1 = __expf(x1 - gm);
    float ssum = e0 + e1;
    #pragma unroll
    for (int off = 32; off; off >>= 1) ssum += __shfl_xor(ssum, off);
    if (lane == 0) s_red2[wave] = ssum;
    __syncthreads();
    float gs = 0.0f;
    #pragma unroll
    for (int i = 0; i < 8; ++i) gs += s_red2[i];
    const float rgs = 1.0f / gs;

    s_w[tid]       = e0 * rgs;
    s_w[tid + 512] = e1 * rgs;
    __syncthreads();

    // ---- v-reduction over my column slice: attn[c] = sum_l w[l] v[l,c] ----
    const float4* v4 = reinterpret_cast<const float4*>(v + (size_t)b * L * D)
                       + cg * 32;
    const int c = tid & 31;           // float4 column within slice
    const int g = tid >> 5;           // row group 0..15
    float4 acc0 = make_float4(0.f, 0.f, 0.f, 0.f);
    float4 acc1 = make_float4(0.f, 0.f, 0.f, 0.f);
    #pragma unroll 4
    for (int it = 0; it < 64; it += 2) {
        const int l0 = it * 16 + g;
        const int l1 = l0 + 16;
        const float w0 = s_w[l0];
        const float w1 = s_w[l1];
        const float4 va = v4[(size_t)l0 * DV + c];
        const float4 vb = v4[(size_t)l1 * DV + c];
        acc0.x += w0 * va.x; acc0.y += w0 * va.y;
        acc0.z += w0 * va.z; acc0.w += w0 * va.w;
        acc1.x += w1 * vb.x; acc1.y += w1 * vb.y;
        acc1.z += w1 * vb.z; acc1.w += w1 * vb.w;
    }
    acc0.x += acc1.x; acc0.y += acc1.y; acc0.z += acc1.z; acc0.w += acc1.w;
    s_acc[g][c] = acc0;
    __syncthreads();

    if (tid < 32) {
        float4 a = s_acc[0][tid];
        #pragma unroll
        for (int gg = 1; gg < 16; ++gg) {
            const float4 p = s_acc[gg][tid];
            a.x += p.x; a.y += p.y; a.z += p.z; a.w += p.w;
        }
        s_attn[tid] = a;
    }
    __syncthreads();

    // ---- write out[l, slice] = gate[l] * attn for all l (NT streaming) ----
    float4* out4 = reinterpret_cast<float4*>(out + (size_t)b * L * D) + cg * 32;
    #pragma unroll 4
    for (int i = tid; i < L * 32; i += 512) {
        const int l  = i >> 5;
        const int cc = i & 31;
        const float sg = s_gate[l];
        const float4 a = s_attn[cc];
        nt_store4(&out4[(size_t)l * DV + cc],
                  make_float4(sg * a.x, sg * a.y, sg * a.z, sg * a.w));
    }
}

extern "C" void kernel_launch(void* const* d_in, const int* in_sizes, int n_in,
                              void* d_out, int out_size, void* d_ws, size_t ws_size,
                              hipStream_t stream) {
    const float* q  = (const float*)d_in[0];
    const float* kc = (const float*)d_in[1];
    const float* kd = (const float*)d_in[2];
    const float* v  = (const float*)d_in[3];
    float* out    = (float*)d_out;                       // (B,L,D) flat
    float* logits = out + (size_t)B * L * D;             // (B,L) flat

    float* gates = (float*)d_ws;                         // B*L floats = 1 MB

    hipLaunchKernelGGL(cda_k1_logits, dim3(B * 8), dim3(256), 0, stream,
                       q, kc, kd, logits, gates);
    hipLaunchKernelGGL(cda_k23, dim3(B * 4), dim3(512), 0, stream,
                       logits, gates, v, out);
}